// Round 2
// baseline (114.522 us; speedup 1.0000x reference)
//
#include <hip/hip_runtime.h>

// PartitionPadding: out[m][p][:] = feat[starts[m]+p][:] if starts[m]+p < starts[m+1] else 0.
// B=2048, MAX_ATOMS=640, D=64. Pure data movement: 256MB read + 335.5MB write.

#define BATCH 2048
#define MAXA  640
#define DF    64

// starts[] via boundary detection on the sorted indicator (parallel, no dep chain).
// For each i where ind[i] != ind[i-1]: starts[m] = i for m in (ind[i-1], ind[i]].
// Edges: m <= ind[0] -> 0 ; m > ind[N-1] -> N.
__global__ void pp_starts_kernel(const int* __restrict__ ind, int N,
                                 int* __restrict__ starts) {
    int stride = gridDim.x * blockDim.x;
    for (int i = blockIdx.x * blockDim.x + threadIdx.x; i < N; i += stride) {
        int cur  = ind[i];
        int prev = (i == 0) ? -1 : ind[i - 1];
        if (cur != prev) {
            for (int m = prev + 1; m <= cur; ++m) starts[m] = i;
        }
        if (i == N - 1) {
            for (int m = cur + 1; m <= BATCH; ++m) starts[m] = N;
        }
    }
}

// Gather+pad. Each thread handles two rows (p, p+320) of one molecule:
// 2 independent 16B load/store pairs -> double memory ILP.
// grid = (MAXA*16/(2*256) = 20, BATCH), block = 256.
__global__ __launch_bounds__(256) void pp_gather_kernel(
        const float4* __restrict__ feat,
        const int* __restrict__ starts,
        float4* __restrict__ out) {
    const unsigned m   = blockIdx.y;
    const unsigned idx = blockIdx.x * 256u + threadIdx.x;  // 0 .. 5119
    const unsigned p0  = idx >> 4;       // 0 .. 319
    const unsigned q   = idx & 15u;      // float4 within row
    const int s = starts[m];
    const int e = starts[m + 1];

    const unsigned src0 = (unsigned)s + p0;
    const unsigned src1 = src0 + 320u;

    float4 v0 = make_float4(0.f, 0.f, 0.f, 0.f);
    float4 v1 = make_float4(0.f, 0.f, 0.f, 0.f);
    if ((int)src0 < e) v0 = feat[src0 * 16u + q];
    if ((int)src1 < e) v1 = feat[src1 * 16u + q];

    const unsigned obase = m * (MAXA * 16u) + p0 * 16u + q;
    out[obase]            = v0;
    out[obase + 320u*16u] = v1;
}

extern "C" void kernel_launch(void* const* d_in, const int* in_sizes, int n_in,
                              void* d_out, int out_size, void* d_ws, size_t ws_size,
                              hipStream_t stream) {
    const float* feat = (const float*)d_in[0];
    const int*   ind  = (const int*)d_in[1];
    float*       out  = (float*)d_out;
    int*         starts = (int*)d_ws;   // BATCH+1 ints

    const int N = in_sizes[0] / DF;

    // 1) starts via parallel boundary detect (~8MB mostly-cached reads)
    {
        int blocks = min((N + 255) / 256, 4096);
        pp_starts_kernel<<<blocks, 256, 0, stream>>>(ind, N, starts);
    }

    // 2) dense gather+pad: every output element written each call
    {
        dim3 grid(MAXA * (DF / 4) / (2 * 256), BATCH);  // (20, 2048)
        pp_gather_kernel<<<grid, 256, 0, stream>>>(
            (const float4*)feat, starts, (float4*)out);
    }
}